// Round 11
// baseline (55.200 us; speedup 1.0000x reference)
//
#include <hip/hip_runtime.h>

#define NN 4096
#define DD 256
#define MARGIN 0.5f

typedef __attribute__((ext_vector_type(8))) short bf16x8;  // 8 bf16 (4 VGPRs)
typedef __attribute__((ext_vector_type(4))) float f32x4;   // MFMA C/D

__device__ inline unsigned short f32_to_bf16_rne(float v) {
    unsigned int b = __float_as_uint(v);
    b += 0x7FFFu + ((b >> 16) & 1u);   // round-to-nearest-even
    return (unsigned short)(b >> 16);
}
__device__ inline float bf16_to_f32(unsigned short u) {
    return __uint_as_float(((unsigned int)u) << 16);
}

// ---------------------------------------------------------------------------
// Kernel A: per-row stats + bf16 convert + diagonal corrections.
// pb rows [0,4096)=p1, [4096,8192)=p2. nb[j]=||row_j||^2 (fp32).
// ai[i] = ||p1_i-p2_i||^2 - ||p1_i||^2 + MARGIN (fp32 exact).
// corr[i] = the two diagonal hinge terms (j==i, j==i+NN) from the SAME
// bf16-rounded values in fp32 (validated R7-R10: absmax 0.0).
// ---------------------------------------------------------------------------
__global__ __launch_bounds__(256) void stats_convert(
    const float* __restrict__ p1, const float* __restrict__ p2,
    unsigned short* __restrict__ pb, float* __restrict__ nb,
    float* __restrict__ ai, float* __restrict__ corr)
{
    const int wave = threadIdx.x >> 6;
    const int lane = threadIdx.x & 63;
    const int row  = blockIdx.x * 4 + wave;

    const float4 x = *(const float4*)&p1[(size_t)row * DD + lane * 4];
    const float4 y = *(const float4*)&p2[(size_t)row * DD + lane * 4];

    ushort4 xb, yb;
    xb.x = f32_to_bf16_rne(x.x); xb.y = f32_to_bf16_rne(x.y);
    xb.z = f32_to_bf16_rne(x.z); xb.w = f32_to_bf16_rne(x.w);
    yb.x = f32_to_bf16_rne(y.x); yb.y = f32_to_bf16_rne(y.y);
    yb.z = f32_to_bf16_rne(y.z); yb.w = f32_to_bf16_rne(y.w);
    *(ushort4*)&pb[(size_t)row * DD + lane * 4] = xb;
    *(ushort4*)&pb[(size_t)(NN + row) * DD + lane * 4] = yb;

    float s1 = x.x*x.x + x.y*x.y + x.z*x.z + x.w*x.w;
    float s2 = y.x*y.x + y.y*y.y + y.z*y.z + y.w*y.w;
    float dx = x.x-y.x, dy = x.y-y.y, dz = x.z-y.z, dw = x.w-y.w;
    float sa = dx*dx + dy*dy + dz*dz + dw*dw;

    float xf0 = bf16_to_f32(xb.x), xf1 = bf16_to_f32(xb.y),
          xf2 = bf16_to_f32(xb.z), xf3 = bf16_to_f32(xb.w);
    float yf0 = bf16_to_f32(yb.x), yf1 = bf16_to_f32(yb.y),
          yf2 = bf16_to_f32(yb.z), yf3 = bf16_to_f32(yb.w);
    float s1b  = xf0*xf0 + xf1*xf1 + xf2*xf2 + xf3*xf3;
    float s12b = xf0*yf0 + xf1*yf1 + xf2*yf2 + xf3*yf3;

    #pragma unroll
    for (int off = 32; off > 0; off >>= 1) {
        s1  += __shfl_down(s1,  off);
        s2  += __shfl_down(s2,  off);
        sa  += __shfl_down(sa,  off);
        s1b += __shfl_down(s1b, off);
        s12b+= __shfl_down(s12b,off);
    }
    if (lane == 0) {
        nb[row]      = s1;
        nb[NN + row] = s2;
        ai[row]      = sa - s1 + MARGIN;
        const float t1 = fmaxf(sa - 2.f*s1 + MARGIN + 2.f*s1b, 0.f);
        const float t2 = fmaxf(sa - s1 - s2 + MARGIN + 2.f*s12b, 0.f);
        corr[row] = t1 + t2;
    }
}

// ---------------------------------------------------------------------------
// Kernel B: R5-exact structure (fastest measured) + in-tile b-prefetch.
// 512 blocks x 256 thr (4 waves 2Mx2N), 2 blocks/CU. A = 64 rows x full K
// in regs per wave (a[4][8]); B double-buffered LDS (2 x 32 KB) via
// global_load_lds w=16 with rule-21 both-sides XOR swizzle. ONE plain
// __syncthreads per j-tile (R10 proved asm vmcnt/sched_barrier pinning
// regresses; R8 proved __threadfence regresses). NEW vs R5: explicit
// one-step software pipeline of the B-fragment ds_reads (read kq+1 while
// MFMAing kq) so LDS latency hides under the MFMA chain instead of
// stalling each kq step.
// Epilogue unconditional; diagonals subtracted via corr[] in final_reduce.
// ---------------------------------------------------------------------------
__global__ __launch_bounds__(256, 2) void gemm_hinge(
    const unsigned short* __restrict__ pb,
    const float* __restrict__ nb, const float* __restrict__ ai,
    float* __restrict__ partial)
{
    __shared__ unsigned short Bs[2][64 * 256];   // 2 x 32 KB
    __shared__ float wsum[4];

    const int t    = threadIdx.x;
    const int lane = t & 63;
    const int wave = t >> 6;       // 0..3
    const int wm   = wave >> 1;    // 0..1 (M)
    const int wn   = wave & 1;     // 0..1 (N)

    // R5 XCD-bijective swizzle (512 = 8 XCD x 64): XCD x owns istripes
    // 4x..4x+3; all 16 jgroups of a stripe on one XCD.
    const int bid     = blockIdx.x;
    const int istripe = (bid & 7) * 4 + (bid >> 7);   // 0..31
    const int jgroup  = (bid >> 3) & 15;              // 0..15
    const int i0      = istripe * 128;
    const int jt0     = jgroup * 8;

    const int lr = lane & 15;      // A row / B col within 16
    const int l4 = lane >> 4;      // 0..3
    const int lk = l4 * 8;         // k offset of lane's 8 contiguous bf16

    // ---- B staging (rule-21 both-sides XOR swizzle, linear LDS dest) ----
    auto stage = [&](int sel, int jt) {
        const unsigned short* base = pb + (size_t)jt * 64 * DD;
        #pragma unroll
        for (int q = 0; q < 8; ++q) {
            const int c   = q * 256 + t;
            const int row = c >> 5;
            const int cw  = c & 31;
            const unsigned short* g = base + row * DD + ((cw ^ (row & 7)) * 8);
            __builtin_amdgcn_global_load_lds(
                (const __attribute__((address_space(1))) unsigned int*)g,
                (__attribute__((address_space(3))) unsigned int*)
                    &Bs[sel][(q * 256 + wave * 64) * 8],
                16, 0, 0);
        }
    };

    stage(0, jt0);

    // ---- A fragments in registers: rows i0 + wm*64 + m*16 + lr, full K ----
    bf16x8 a[4][8];
    #pragma unroll
    for (int m = 0; m < 4; ++m) {
        const unsigned short* ar = pb + (size_t)(i0 + wm * 64 + m * 16 + lr) * DD + lk;
        #pragma unroll
        for (int kq = 0; kq < 8; ++kq)
            a[m][kq] = *(const bf16x8*)(ar + kq * 32);
    }

    // ---- ai / nb preload ----
    const int r0 = l4 * 4;
    float aiv[4][4];
    #pragma unroll
    for (int m = 0; m < 4; ++m)
        #pragma unroll
        for (int r = 0; r < 4; ++r)
            aiv[m][r] = ai[i0 + wm * 64 + m * 16 + r0 + r];

    float nbv[8][2];
    #pragma unroll
    for (int jj = 0; jj < 8; ++jj)
        #pragma unroll
        for (int n = 0; n < 2; ++n)
            nbv[jj][n] = nb[jgroup * 512 + jj * 64 + wn * 32 + n * 16 + lr];

    __syncthreads();

    float lsum = 0.f;
    int sel = 0;

    for (int jj = 0; jj < 8; ++jj) {
        if (jj < 7) stage(sel ^ 1, jt0 + jj + 1);

        f32x4 acc[4][2];
        #pragma unroll
        for (int m = 0; m < 4; ++m)
            #pragma unroll
            for (int n = 0; n < 2; ++n)
                acc[m][n] = (f32x4){0.f, 0.f, 0.f, 0.f};

        // ---- b-fragment software pipeline: read kq+1 while MFMAing kq ----
        bf16x8 bcur[2], bnxt[2];
        #pragma unroll
        for (int n = 0; n < 2; ++n) {
            const int row = wn * 32 + n * 16 + lr;
            bcur[n] = *(const bf16x8*)&Bs[sel][row * 256 + ((l4 ^ (row & 7)) * 8)];
        }
        #pragma unroll
        for (int kq = 0; kq < 8; ++kq) {
            if (kq < 7) {
                #pragma unroll
                for (int n = 0; n < 2; ++n) {
                    const int row = wn * 32 + n * 16 + lr;
                    const int cl  = (kq + 1) * 4 + l4;
                    bnxt[n] = *(const bf16x8*)
                        &Bs[sel][row * 256 + ((cl ^ (row & 7)) * 8)];
                }
            }
            #pragma unroll
            for (int m = 0; m < 4; ++m)
                #pragma unroll
                for (int n = 0; n < 2; ++n)
                    acc[m][n] = __builtin_amdgcn_mfma_f32_16x16x32_bf16(
                        a[m][kq], bcur[n], acc[m][n], 0, 0, 0);
            #pragma unroll
            for (int n = 0; n < 2; ++n) bcur[n] = bnxt[n];
        }

        // ---- hinge epilogue (registers only; unconditional) ----
        #pragma unroll
        for (int n = 0; n < 2; ++n) {
            const float nbj = nbv[jj][n];
            #pragma unroll
            for (int m = 0; m < 4; ++m)
                #pragma unroll
                for (int r = 0; r < 4; ++r)
                    lsum += fmaxf(fmaf(2.f, acc[m][n][r], aiv[m][r] - nbj), 0.f);
        }

        __syncthreads();   // drains stage(jj+1) + all Bs[sel] reads; swap safe
        sel ^= 1;
    }

    // ---- block reduction (deterministic) ----
    #pragma unroll
    for (int off = 32; off > 0; off >>= 1) lsum += __shfl_down(lsum, off);
    if (lane == 0) wsum[wave] = lsum;
    __syncthreads();
    if (t == 0)
        partial[bid] = wsum[0] + wsum[1] + wsum[2] + wsum[3];
}

// ---------------------------------------------------------------------------
// Kernel C: sum partials, subtract diagonal corrections, scale, write scalar.
// ---------------------------------------------------------------------------
__global__ __launch_bounds__(256) void final_reduce(
    const float* __restrict__ partial, const float* __restrict__ corr,
    float* __restrict__ out, float scale)
{
    const int t = threadIdx.x;
    float s = 0.f;
    for (int i = t; i < 512; i += 256) s += partial[i];
    for (int i = t; i < NN; i += 256) s -= corr[i];
    #pragma unroll
    for (int off = 32; off > 0; off >>= 1) s += __shfl_down(s, off);
    __shared__ float w[4];
    if ((t & 63) == 0) w[t >> 6] = s;
    __syncthreads();
    if (t == 0) out[0] = (w[0] + w[1] + w[2] + w[3]) * scale;
}

// ---------------------------------------------------------------------------
extern "C" void kernel_launch(void* const* d_in, const int* in_sizes, int n_in,
                              void* d_out, int out_size, void* d_ws, size_t ws_size,
                              hipStream_t stream) {
    const float* p1 = (const float*)d_in[0];
    const float* p2 = (const float*)d_in[1];
    float* out = (float*)d_out;

    char* ws = (char*)d_ws;
    unsigned short* pb = (unsigned short*)ws;                       // 4 MB (8192x256 bf16)
    float* nb      = (float*)(ws + (size_t)2 * NN * DD * 2);        // 32 KB
    float* ai      = nb + 2 * NN;                                   // 16 KB
    float* corr    = ai + NN;                                       // 16 KB
    float* partial = corr + NN;                                     // 2 KB
    const float scale = 1.0f / ((float)NN * (float)(NN - 1));

    stats_convert<<<NN / 4, 256, 0, stream>>>(p1, p2, pb, nb, ai, corr);
    gemm_hinge<<<512, 256, 0, stream>>>(pb, nb, ai, partial);
    final_reduce<<<1, 256, 0, stream>>>(partial, corr, out, scale);
}

// Round 12
// 38.485 us; speedup vs baseline: 1.4343x; 1.4343x over previous
//
#include <hip/hip_runtime.h>

#define NN 4096
#define DD 256
#define MARGIN 0.5f

typedef __attribute__((ext_vector_type(8))) short bf16x8;  // 8 bf16 (4 VGPRs)
typedef __attribute__((ext_vector_type(4))) float f32x4;   // MFMA C/D

__device__ inline unsigned short f32_to_bf16_rne(float v) {
    unsigned int b = __float_as_uint(v);
    b += 0x7FFFu + ((b >> 16) & 1u);   // round-to-nearest-even
    return (unsigned short)(b >> 16);
}

// ---------------------------------------------------------------------------
// Kernel A: per-row stats + bf16 convert (R5-exact) + ticket reset.
// pb rows [0,4096)=p1, [4096,8192)=p2. nb[j]=||row_j||^2 (fp32).
// ai[i] = ||p1_i-p2_i||^2 - ||p1_i||^2 + MARGIN (exact fp32).
// ---------------------------------------------------------------------------
__global__ __launch_bounds__(256) void stats_convert(
    const float* __restrict__ p1, const float* __restrict__ p2,
    unsigned short* __restrict__ pb, float* __restrict__ nb,
    float* __restrict__ ai, unsigned int* __restrict__ ctr)
{
    if (blockIdx.x == 0 && threadIdx.x == 0) *ctr = 0u;   // replay-safe reset

    const int wave = threadIdx.x >> 6;
    const int lane = threadIdx.x & 63;
    const int row  = blockIdx.x * 4 + wave;

    const float4 x = *(const float4*)&p1[(size_t)row * DD + lane * 4];
    const float4 y = *(const float4*)&p2[(size_t)row * DD + lane * 4];

    ushort4 xb, yb;
    xb.x = f32_to_bf16_rne(x.x); xb.y = f32_to_bf16_rne(x.y);
    xb.z = f32_to_bf16_rne(x.z); xb.w = f32_to_bf16_rne(x.w);
    yb.x = f32_to_bf16_rne(y.x); yb.y = f32_to_bf16_rne(y.y);
    yb.z = f32_to_bf16_rne(y.z); yb.w = f32_to_bf16_rne(y.w);
    *(ushort4*)&pb[(size_t)row * DD + lane * 4] = xb;
    *(ushort4*)&pb[(size_t)(NN + row) * DD + lane * 4] = yb;

    float s1 = x.x*x.x + x.y*x.y + x.z*x.z + x.w*x.w;
    float s2 = y.x*y.x + y.y*y.y + y.z*y.z + y.w*y.w;
    float dx = x.x-y.x, dy = x.y-y.y, dz = x.z-y.z, dw = x.w-y.w;
    float sa = dx*dx + dy*dy + dz*dz + dw*dw;

    #pragma unroll
    for (int off = 32; off > 0; off >>= 1) {
        s1 += __shfl_down(s1, off);
        s2 += __shfl_down(s2, off);
        sa += __shfl_down(sa, off);
    }
    if (lane == 0) {
        nb[row]      = s1;
        nb[NN + row] = s2;
        ai[row]      = sa - s1 + MARGIN;
    }
}

// ---------------------------------------------------------------------------
// Kernel B: R5-EXACT register-resident-A GEMM + fused hinge (proven 36.4),
// plus a merged last-block final reduction using agent-scope write-through
// atomics ONLY (no __threadfence: R8 showed its cache-invalidate costs
// ~16 us across 512 blocks; scoped atomic stores don't invalidate).
// 512 blocks x 256 thr (4 waves 2Mx2N), 2 blocks/CU. A = 64 rows x full K
// in regs per wave (a[4][8]); B double-buffered LDS (2 x 32 KB) via
// global_load_lds w=16 with rule-21 both-sides XOR swizzle; ONE plain
// __syncthreads per j-tile. Conditional diagonal-skip epilogue (R5-exact).
// ---------------------------------------------------------------------------
__global__ __launch_bounds__(256, 2) void gemm_hinge(
    const unsigned short* __restrict__ pb,
    const float* __restrict__ nb, const float* __restrict__ ai,
    float* __restrict__ partial, unsigned int* __restrict__ ctr,
    float* __restrict__ out, float scale)
{
    __shared__ unsigned short Bs[2][64 * 256];   // 2 x 32 KB
    __shared__ float wsum[4];
    __shared__ int is_last;

    const int t    = threadIdx.x;
    const int lane = t & 63;
    const int wave = t >> 6;       // 0..3
    const int wm   = wave >> 1;    // 0..1 (M)
    const int wn   = wave & 1;     // 0..1 (N)

    // R5 XCD-bijective swizzle (512 = 8 XCD x 64): XCD x owns istripes
    // 4x..4x+3; all 16 jgroups of a stripe on one XCD.
    const int bid     = blockIdx.x;
    const int istripe = (bid & 7) * 4 + (bid >> 7);   // 0..31
    const int jgroup  = (bid >> 3) & 15;              // 0..15
    const int i0      = istripe * 128;
    const int jt0     = jgroup * 8;

    const int lr = lane & 15;      // A row / B col within 16
    const int l4 = lane >> 4;      // 0..3
    const int lk = l4 * 8;         // k offset of lane's 8 contiguous bf16

    // ---- A fragments in registers: rows i0 + wm*64 + m*16 + lr, full K ----
    bf16x8 a[4][8];
    #pragma unroll
    for (int m = 0; m < 4; ++m) {
        const unsigned short* ar = pb + (size_t)(i0 + wm * 64 + m * 16 + lr) * DD;
        #pragma unroll
        for (int kq = 0; kq < 8; ++kq)
            a[m][kq] = *(const bf16x8*)(ar + kq * 32 + lk);
    }

    // ---- ai preload (this lane's 16 fixed i-rows) ----
    const int r0 = l4 * 4;
    float aiv[4][4];
    #pragma unroll
    for (int m = 0; m < 4; ++m)
        #pragma unroll
        for (int r = 0; r < 4; ++r)
            aiv[m][r] = ai[i0 + wm * 64 + m * 16 + r0 + r];

    // ---- B staging (rule-21 both-sides XOR swizzle, linear LDS dest) ----
    auto stage = [&](int sel, int jt) {
        const unsigned short* base = pb + (size_t)jt * 64 * DD;
        #pragma unroll
        for (int q = 0; q < 8; ++q) {
            const int c   = q * 256 + t;
            const int row = c >> 5;
            const int cw  = c & 31;
            const unsigned short* g = base + row * DD + ((cw ^ (row & 7)) * 8);
            __builtin_amdgcn_global_load_lds(
                (const __attribute__((address_space(1))) unsigned int*)g,
                (__attribute__((address_space(3))) unsigned int*)
                    &Bs[sel][(q * 256 + wave * 64) * 8],
                16, 0, 0);
        }
    };

    float lsum = 0.f;

    stage(0, jt0);
    __syncthreads();

    int sel = 0;
    for (int jj = 0; jj < 8; ++jj) {
        const int j0 = (jt0 + jj) * 64;
        if (jj < 7) stage(sel ^ 1, jt0 + jj + 1);

        f32x4 acc[4][2];
        #pragma unroll
        for (int m = 0; m < 4; ++m)
            #pragma unroll
            for (int n = 0; n < 2; ++n)
                acc[m][n] = (f32x4){0.f, 0.f, 0.f, 0.f};

        #pragma unroll
        for (int kq = 0; kq < 8; ++kq) {
            bf16x8 b[2];
            #pragma unroll
            for (int n = 0; n < 2; ++n) {
                const int row = wn * 32 + n * 16 + lr;
                const int cl  = kq * 4 + l4;
                b[n] = *(const bf16x8*)&Bs[sel][row * 256 + ((cl ^ (row & 7)) * 8)];
            }
            #pragma unroll
            for (int m = 0; m < 4; ++m)
                #pragma unroll
                for (int n = 0; n < 2; ++n)
                    acc[m][n] = __builtin_amdgcn_mfma_f32_16x16x32_bf16(
                        a[m][kq], b[n], acc[m][n], 0, 0, 0);
        }

        // ---- hinge epilogue (R5-exact: conditional diagonal skip) ----
        #pragma unroll
        for (int n = 0; n < 2; ++n) {
            const int j     = j0 + wn * 32 + n * 16 + lr;
            const float nbj = nb[j];
            #pragma unroll
            for (int m = 0; m < 4; ++m) {
                #pragma unroll
                for (int r = 0; r < 4; ++r) {
                    const int i = i0 + wm * 64 + m * 16 + r0 + r;
                    float h = fmaf(2.f, acc[m][n][r], aiv[m][r] - nbj);
                    h = fmaxf(h, 0.f);
                    if (j != i && j != i + NN) lsum += h;
                }
            }
        }

        __syncthreads();   // drains stage(jj+1) + all Bs reads; swap safe
        sel ^= 1;
    }

    // ---- block reduction (deterministic) ----
    #pragma unroll
    for (int off = 32; off > 0; off >>= 1) lsum += __shfl_down(lsum, off);
    if (lane == 0) wsum[wave] = lsum;
    __syncthreads();

    // ---- publish partial with write-through agent-scope store (no fence),
    //      then take a ticket; unique last block reduces in fixed order. ----
    if (t == 0) {
        const float ps = wsum[0] + wsum[1] + wsum[2] + wsum[3];
        __hip_atomic_store(&partial[bid], ps, __ATOMIC_RELAXED,
                           __HIP_MEMORY_SCOPE_AGENT);
        asm volatile("s_waitcnt vmcnt(0)" ::: "memory");  // store acked at L2-CP
        const unsigned int prev = __hip_atomic_fetch_add(
            ctr, 1u, __ATOMIC_RELAXED, __HIP_MEMORY_SCOPE_AGENT);
        is_last = (prev == 511u);
    }
    __syncthreads();

    if (is_last) {
        float s = 0.f;
        for (int i = t; i < 512; i += 256)
            s += __hip_atomic_load(&partial[i], __ATOMIC_RELAXED,
                                   __HIP_MEMORY_SCOPE_AGENT);
        #pragma unroll
        for (int off = 32; off > 0; off >>= 1) s += __shfl_down(s, off);
        if (lane == 0) wsum[wave] = s;
        __syncthreads();
        if (t == 0)
            out[0] = (wsum[0] + wsum[1] + wsum[2] + wsum[3]) * scale;
    }
}

// ---------------------------------------------------------------------------
extern "C" void kernel_launch(void* const* d_in, const int* in_sizes, int n_in,
                              void* d_out, int out_size, void* d_ws, size_t ws_size,
                              hipStream_t stream) {
    const float* p1 = (const float*)d_in[0];
    const float* p2 = (const float*)d_in[1];
    float* out = (float*)d_out;

    char* ws = (char*)d_ws;
    unsigned short* pb = (unsigned short*)ws;                       // 4 MB (8192x256 bf16)
    float* nb      = (float*)(ws + (size_t)2 * NN * DD * 2);        // 32 KB
    float* ai      = nb + 2 * NN;                                   // 16 KB
    float* partial = ai + NN;                                       // 2 KB
    unsigned int* ctr = (unsigned int*)(partial + 512);             // 4 B
    const float scale = 1.0f / ((float)NN * (float)(NN - 1));

    stats_convert<<<NN / 4, 256, 0, stream>>>(p1, p2, pb, nb, ai, ctr);
    gemm_hinge<<<512, 256, 0, stream>>>(pb, nb, ai, partial, ctr, out, scale);
}